// Round 4
// baseline (152.127 us; speedup 1.0000x reference)
//
#include <hip/hip_runtime.h>

#define BATCH 32
#define HDIM 224
#define WDIM 224
#define CDIM 3
#define KTOT (HDIM * WDIM * CDIM)   // 150528
#define HID 64
#define KCHUNK 256
#define NBLK1 (KTOT / KCHUNK)       // 588
#define PIX (HDIM * WDIM)           // 50176
#define BLK3 49                      // blocks per batch: 256 thr * 4 px = 1024 px

// ---------------- Kernel 1: part[blk] = flat[:,kslice] @ w1[kslice,:] --------
// Block: 256 thr = 4 waves, owns k-range [k0, k0+256). Wave w owns 64 k's.
// Thread: lane = hid, accumulates all 32 batches. NO atomics: block-reduced
// partials are streamed to part[blk][2048] and summed by k1_reduce.
__global__ __launch_bounds__(256, 4) void k1_gemm(const float* __restrict__ flat,
                                                  const float* __restrict__ w1,
                                                  float* __restrict__ part) {
    __shared__ float smem[8192];                 // 32 KB dual-purpose
    const int tid  = threadIdx.x;
    const int lane = tid & 63;                   // hid
    const int wave = tid >> 6;
    const int k0   = blockIdx.x * KCHUNK;
    const int kw   = wave * 64;

    // --- Prefetch w1[k0+kw .. +64)[lane] into registers (64 indep loads) ---
    float w[64];
    const float* wp = w1 + (size_t)(k0 + kw) * HID + lane;
#pragma unroll
    for (int i = 0; i < 64; ++i)
        w[i] = wp[(size_t)i * HID];

    // --- Stage flat[32][k0..k0+256) into LDS (32 KB), coalesced float4 ---
#pragma unroll
    for (int t = 0; t < 8; ++t) {
        const int idx = tid + t * 256;           // 0..2047 float4 slots
        const int b   = idx >> 6;                // 0..31
        const int kq  = idx & 63;                // float4 index within row
        *(float4*)(smem + b * 256 + kq * 4) =
            *(const float4*)(flat + (size_t)b * KTOT + k0 + kq * 4);
    }
    __syncthreads();                             // drains w-prefetch too

    float acc[32];
#pragma unroll
    for (int j = 0; j < 32; ++j) acc[j] = 0.0f;

#pragma unroll
    for (int kk = 0; kk < 64; kk += 4) {
#pragma unroll
        for (int b = 0; b < 32; ++b) {
            const float4 x = *(const float4*)(smem + b * 256 + kw + kk);
            float a = acc[b];
            a = fmaf(x.x, w[kk + 0], a);
            a = fmaf(x.y, w[kk + 1], a);
            a = fmaf(x.z, w[kk + 2], a);
            a = fmaf(x.w, w[kk + 3], a);
            acc[b] = a;
        }
    }
    __syncthreads();                             // flat slice fully consumed

    // --- Cross-wave reduce in LDS, then stream partials (no atomics) ---
#pragma unroll
    for (int j = 0; j < 32; ++j)
        smem[wave * 2048 + j * 64 + lane] = acc[j];
    __syncthreads();

    float* po = part + (size_t)blockIdx.x * 2048;
#pragma unroll
    for (int t = 0; t < 8; ++t) {
        const int idx = tid + t * 256;           // 0..2047 = b*64+hid
        po[idx] = smem[idx] + smem[2048 + idx] +
                  smem[4096 + idx] + smem[6144 + idx];
    }
}

// ---------------- Kernel 1b: hacc = sum over 588 blocks of part --------------
__global__ __launch_bounds__(256) void k1_reduce(const float* __restrict__ part,
                                                 float* __restrict__ hacc) {
    __shared__ float red[256];
    const int tid    = threadIdx.x;
    const int o      = tid & 31;                 // output within block's 32
    const int g      = tid >> 5;                 // 0..7 reduction group
    const int o_base = blockIdx.x * 32;

    float s = 0.0f;
    for (int blk = g; blk < NBLK1; blk += 8)
        s += part[(size_t)blk * 2048 + o_base + o];
    red[tid] = s;
    __syncthreads();
    if (g == 0) {
        float t = 0.0f;
#pragma unroll
        for (int gg = 0; gg < 8; ++gg)
            t += red[gg * 32 + o];
        hacc[o_base + o] = t;
    }
}

// -------- Kernel 3: head recompute + affine grid + bilinear sampling --------
__global__ __launch_bounds__(256) void k3_sample(const float* __restrict__ img,
                                                 const float* __restrict__ hacc,
                                                 const float* __restrict__ b1,
                                                 const float* __restrict__ w2,
                                                 const float* __restrict__ b2,
                                                 float* __restrict__ out) {
    const int b     = blockIdx.x / BLK3;
    const int strip = blockIdx.x - b * BLK3;
    const int tid   = threadIdx.x;

    __shared__ float sh[HID];
    __shared__ float sth[6];
    if (tid < HID)
        sh[tid] = tanhf(hacc[b * HID + tid] + b1[tid]);
    __syncthreads();
    if (tid < 6) {
        float s = b2[tid];
#pragma unroll
        for (int t = 0; t < HID; ++t)
            s = fmaf(sh[t], w2[t * 6 + tid], s);
        sth[tid] = tanhf(s);
    }
    __syncthreads();

    const float t0 = sth[0], t1 = sth[1], t2 = sth[2];
    const float t3 = sth[3], t4 = sth[4], t5 = sth[5];

    const float* base = img + (size_t)b * KTOT;
    const int pix0 = strip * 1024 + tid * 4;

    float res[12];
#pragma unroll
    for (int p = 0; p < 4; ++p) {
        const int pix = pix0 + p;
        const int i = pix / WDIM;
        const int j = pix - i * WDIM;

        const float xt = (2.0f * (float)j - (float)(WDIM - 1)) / (float)(WDIM - 1);
        const float yt = (2.0f * (float)i - (float)(HDIM - 1)) / (float)(HDIM - 1);

        const float xs = t0 * xt + t1 * yt + t2;
        const float ys = t3 * xt + t4 * yt + t5;

        const float x = 0.5f * (xs + 1.0f) * (float)(WDIM - 1);
        const float y = 0.5f * (ys + 1.0f) * (float)(HDIM - 1);

        const int x0 = (int)floorf(x);
        const int y0 = (int)floorf(y);

        const int x0c = min(max(x0, 0), WDIM - 1);
        const int x1c = min(max(x0 + 1, 0), WDIM - 1);
        const int y0c = min(max(y0, 0), HDIM - 1);
        const int y1c = min(max(y0 + 1, 0), HDIM - 1);

        // Reference computes weights from the CLIPPED corner coordinates.
        const float x0f = (float)x0c, x1f = (float)x1c;
        const float y0f = (float)y0c, y1f = (float)y1c;

        const float wa = (x1f - x) * (y1f - y);
        const float wb = (x1f - x) * (y - y0f);
        const float wc = (x - x0f) * (y1f - y);
        const float wd = (x - x0f) * (y - y0f);

        const float* pa = base + (size_t)(y0c * WDIM + x0c) * 3;
        const float* pb = base + (size_t)(y1c * WDIM + x0c) * 3;
        const float* pc = base + (size_t)(y0c * WDIM + x1c) * 3;
        const float* pd = base + (size_t)(y1c * WDIM + x1c) * 3;

#pragma unroll
        for (int c = 0; c < 3; ++c)
            res[p * 3 + c] = wa * pa[c] + wb * pb[c] + wc * pc[c] + wd * pd[c];
    }

    float4* po = (float4*)(out + (size_t)b * KTOT + (size_t)pix0 * 3);
    po[0] = make_float4(res[0], res[1], res[2],  res[3]);
    po[1] = make_float4(res[4], res[5], res[6],  res[7]);
    po[2] = make_float4(res[8], res[9], res[10], res[11]);
}

extern "C" void kernel_launch(void* const* d_in, const int* in_sizes, int n_in,
                              void* d_out, int out_size, void* d_ws, size_t ws_size,
                              hipStream_t stream) {
    const float* inputs = (const float*)d_in[0];
    const float* w1     = (const float*)d_in[1];
    const float* b1     = (const float*)d_in[2];
    const float* w2     = (const float*)d_in[3];
    const float* b2     = (const float*)d_in[4];
    float* out = (float*)d_out;

    float* part = (float*)d_ws;                       // 588 * 2048 floats
    float* hacc = part + (size_t)NBLK1 * 2048;        // 32*64 floats

    k1_gemm<<<NBLK1, 256, 0, stream>>>(inputs, w1, part);
    k1_reduce<<<HID * BATCH / 32, 256, 0, stream>>>(part, hacc);
    k3_sample<<<BATCH * BLK3, 256, 0, stream>>>(inputs, hacc, b1, w2, b2, out);
}